// Round 1
// baseline (267.592 us; speedup 1.0000x reference)
//
#include <hip/hip_runtime.h>
#include <hip/hip_fp16.h>
#include <math.h>

// Problem constants (fixed by setup_inputs)
#define B_   2
#define N_   256
#define P_   32
#define M_   16
#define C_   128
#define H_   256
#define NP_  (N_ * P_)          // 8192 points per batch
#define ROWS_ (B_ * NP_ * M_)   // 262144 (= out elements, row == out flat index)
#define TM_  64                 // rows per block
#define LDA_ (H_ + 8)           // f16 leading dim pad (+16B) for LDS bank spread

typedef _Float16 half8 __attribute__((ext_vector_type(8)));
typedef float f32x4 __attribute__((ext_vector_type(4)));

// ---------------- prep: transpose W1/W2 to [n][k] and convert to f16 ----------
__global__ void prep_weights_k(const float* __restrict__ W1, const float* __restrict__ W2,
                               _Float16* __restrict__ Wt1, _Float16* __restrict__ Wt2) {
    int idx = blockIdx.x * 256 + threadIdx.x;   // idx = n*256 + k, 65536 total
    int n = idx >> 8;
    int k = idx & 255;
    Wt1[idx] = (_Float16)W1[k * H_ + n];
    Wt2[idx] = (_Float16)W2[k * H_ + n];
}

// ---------------- prep: cond[b,m,h] = psf[b,m,:] @ Wc + bc (fp32) -------------
__global__ void prep_cond_k(const float* __restrict__ psf, const float* __restrict__ Wc,
                            const float* __restrict__ bc, float* __restrict__ cond) {
#pragma clang fp contract(off)
    int bm = blockIdx.x;        // 0..B*M-1
    int h  = threadIdx.x;       // 0..255
    const float* p = psf + bm * C_;
    float acc = 0.0f;
    for (int c = 0; c < C_; ++c) acc += p[c] * Wc[c * H_ + h];
    cond[bm * H_ + h] = acc + bc[h];
}

// ---------------- main fused kernel ------------------------------------------
__global__ __launch_bounds__(256, 2)
void occ_main_k(const float* __restrict__ pts,  const float* __restrict__ trans,
                const float* __restrict__ rots, const float* __restrict__ scal,
                const float* __restrict__ Wp,   const float* __restrict__ bp,
                const float* __restrict__ b1v,  const float* __restrict__ b2v,
                const float* __restrict__ Wout, const float* __restrict__ bout,
                const float* __restrict__ cond, const _Float16* __restrict__ Wt1,
                const _Float16* __restrict__ Wt2, float* __restrict__ out) {
#pragma clang fp contract(off)
    __shared__ __align__(16) _Float16 sA1[TM_][LDA_];  // net0 (pre-relu) f16
    __shared__ __align__(16) _Float16 sA2[TM_][LDA_];  // relu(h1) f16
    __shared__ float sR[M_][9];
    __shared__ float sT[M_][3];
    __shared__ float sS[M_][3];
    __shared__ float sXt[TM_][3];
    __shared__ float sFell[TM_];
    __shared__ float sPart[TM_][4];
    __shared__ float sWout[H_];

    const int tid  = threadIdx.x;
    const int base = blockIdx.x * TM_;          // global row base (whole block same b)
    const int b    = base / (NP_ * M_);

    sWout[tid] = Wout[tid];
    if (tid < M_) {
        const int m = tid;
        const float* q = rots + (b * M_ + m) * 4;
        float w = q[0], x = q[1], y = q[2], z = q[3];
        float nrm = sqrtf(w * w + x * x + y * y + z * z);
        w /= nrm; x /= nrm; y /= nrm; z /= nrm;
        sR[m][0] = 1.0f - 2.0f * (y * y + z * z);
        sR[m][1] = 2.0f * (x * y - w * z);
        sR[m][2] = 2.0f * (x * z + w * y);
        sR[m][3] = 2.0f * (x * y + w * z);
        sR[m][4] = 1.0f - 2.0f * (x * x + z * z);
        sR[m][5] = 2.0f * (y * z - w * x);
        sR[m][6] = 2.0f * (x * z - w * y);
        sR[m][7] = 2.0f * (y * z + w * x);
        sR[m][8] = 1.0f - 2.0f * (x * x + y * y);
        const float* tp = trans + (b * M_ + m) * 3;
        sT[m][0] = tp[0]; sT[m][1] = tp[1]; sT[m][2] = tp[2];
        const float* sp = scal + (b * M_ + m) * 3;
        sS[m][0] = sp[0]; sS[m][1] = sp[1]; sS[m][2] = sp[2];
    }
    __syncthreads();

    // stage 0: per-row Xt, F_ell (fp32, contract off)
    if (tid < TM_) {
        const int rg = base + tid;
        const int np = (rg / M_) % NP_;
        const int m  = rg & (M_ - 1);
        const float* p = pts + (b * NP_ + np) * 3;
        float x0 = p[0] - sT[m][0];
        float x1 = p[1] - sT[m][1];
        float x2 = p[2] - sT[m][2];
        float t0 = sR[m][0] * x0 + sR[m][1] * x1 + sR[m][2] * x2;
        float t1 = sR[m][3] * x0 + sR[m][4] * x1 + sR[m][5] * x2;
        float t2 = sR[m][6] * x0 + sR[m][7] * x1 + sR[m][8] * x2;
        sXt[tid][0] = t0; sXt[tid][1] = t1; sXt[tid][2] = t2;
        float v0 = t0 / sS[m][0];
        float v1 = t1 / sS[m][1];
        float v2 = t2 / sS[m][2];
        sFell[tid] = v0 * v0 + v1 * v1 + v2 * v2;
    }
    __syncthreads();

    // stage 1: net0[r][h] = Xt@Wp + bp + cond  ->  sA1 (f16, pre-relu)
    {
        const int h = tid;
        const float wp0 = Wp[h], wp1 = Wp[H_ + h], wp2 = Wp[2 * H_ + h];
        const float bph = bp[h];
        for (int r = 0; r < TM_; ++r) {
            const int m = (base + r) & (M_ - 1);
            float v = sXt[r][0] * wp0 + sXt[r][1] * wp1 + sXt[r][2] * wp2 + bph
                      + cond[(b * M_ + m) * H_ + h];
            sA1[r][h] = (_Float16)v;
        }
    }
    __syncthreads();

    const int w    = tid >> 6;
    const int lane = tid & 63;
    const int quad = lane >> 4;
    const int ln   = lane & 15;

    f32x4 acc[4][4];
    const f32x4 zero = {0.0f, 0.0f, 0.0f, 0.0f};

    // ---------------- GEMM 1: h1 = relu(net0) @ W1 ----------------
    #pragma unroll
    for (int rt = 0; rt < 4; ++rt)
        #pragma unroll
        for (int tc = 0; tc < 4; ++tc) acc[rt][tc] = zero;

    const _Float16* Wb1 = Wt1 + (w * 64) * H_;
    #pragma unroll
    for (int kc = 0; kc < 8; ++kc) {
        const int k0 = kc * 32 + quad * 8;
        half8 a[4], bf[4];
        #pragma unroll
        for (int rt = 0; rt < 4; ++rt) {
            half8 t = *(const half8*)&sA1[rt * 16 + ln][k0];
            #pragma unroll
            for (int j = 0; j < 8; ++j) t[j] = t[j] > (_Float16)0 ? t[j] : (_Float16)0;
            a[rt] = t;
        }
        #pragma unroll
        for (int tc = 0; tc < 4; ++tc)
            bf[tc] = *(const half8*)(Wb1 + (tc * 16 + ln) * H_ + k0);
        #pragma unroll
        for (int rt = 0; rt < 4; ++rt)
            #pragma unroll
            for (int tc = 0; tc < 4; ++tc)
                acc[rt][tc] = __builtin_amdgcn_mfma_f32_16x16x32_f16(a[rt], bf[tc], acc[rt][tc], 0, 0, 0);
    }

    // epilogue 1: relu(h1 + b1) -> sA2 (f16, post-relu)
    #pragma unroll
    for (int tc = 0; tc < 4; ++tc) {
        const int col = w * 64 + tc * 16 + ln;
        const float bb = b1v[col];
        #pragma unroll
        for (int rt = 0; rt < 4; ++rt) {
            #pragma unroll
            for (int rg = 0; rg < 4; ++rg) {
                float v = acc[rt][tc][rg] + bb;
                v = v > 0.0f ? v : 0.0f;
                sA2[rt * 16 + quad * 4 + rg][col] = (_Float16)v;
            }
        }
    }
    __syncthreads();

    // ---------------- GEMM 2: h2 = relu(h1) @ W2 ----------------
    #pragma unroll
    for (int rt = 0; rt < 4; ++rt)
        #pragma unroll
        for (int tc = 0; tc < 4; ++tc) acc[rt][tc] = zero;

    const _Float16* Wb2 = Wt2 + (w * 64) * H_;
    #pragma unroll
    for (int kc = 0; kc < 8; ++kc) {
        const int k0 = kc * 32 + quad * 8;
        half8 a[4], bf[4];
        #pragma unroll
        for (int rt = 0; rt < 4; ++rt)
            a[rt] = *(const half8*)&sA2[rt * 16 + ln][k0];
        #pragma unroll
        for (int tc = 0; tc < 4; ++tc)
            bf[tc] = *(const half8*)(Wb2 + (tc * 16 + ln) * H_ + k0);
        #pragma unroll
        for (int rt = 0; rt < 4; ++rt)
            #pragma unroll
            for (int tc = 0; tc < 4; ++tc)
                acc[rt][tc] = __builtin_amdgcn_mfma_f32_16x16x32_f16(a[rt], bf[tc], acc[rt][tc], 0, 0, 0);
    }

    // epilogue 2: net = net0 + (h2 + b2); occ partial = sum_col relu(net)*Wout
    float rowsum[4][4];
    #pragma unroll
    for (int rt = 0; rt < 4; ++rt)
        #pragma unroll
        for (int rg = 0; rg < 4; ++rg) rowsum[rt][rg] = 0.0f;

    #pragma unroll
    for (int tc = 0; tc < 4; ++tc) {
        const int col = w * 64 + tc * 16 + ln;
        const float bb = b2v[col];
        const float wo = sWout[col];
        #pragma unroll
        for (int rt = 0; rt < 4; ++rt) {
            #pragma unroll
            for (int rg = 0; rg < 4; ++rg) {
                float net = acc[rt][tc][rg] + bb + (float)sA1[rt * 16 + quad * 4 + rg][col];
                net = net > 0.0f ? net : 0.0f;
                rowsum[rt][rg] += net * wo;
            }
        }
    }

    // reduce across the 16 lanes (cols) of each quad, then across waves via LDS
    #pragma unroll
    for (int rt = 0; rt < 4; ++rt) {
        #pragma unroll
        for (int rg = 0; rg < 4; ++rg) {
            float v = rowsum[rt][rg];
            v += __shfl_xor(v, 1, 16);
            v += __shfl_xor(v, 2, 16);
            v += __shfl_xor(v, 4, 16);
            v += __shfl_xor(v, 8, 16);
            if (ln == 0) sPart[rt * 16 + quad * 4 + rg][w] = v;
        }
    }
    __syncthreads();

    if (tid < TM_) {
        float occ = sPart[tid][0] + sPart[tid][1] + sPart[tid][2] + sPart[tid][3] + bout[0];
        float F = (sFell[tid] <= 1.0f) ? occ : -100.0f;
        out[base + tid] = 1.0f / (1.0f + expf(-10.0f * F));
    }
}

// ---------------- launch ------------------------------------------------------
extern "C" void kernel_launch(void* const* d_in, const int* in_sizes, int n_in,
                              void* d_out, int out_size, void* d_ws, size_t ws_size,
                              hipStream_t stream) {
    const float* pts   = (const float*)d_in[0];
    const float* trans = (const float*)d_in[1];
    const float* rots  = (const float*)d_in[2];
    const float* scal  = (const float*)d_in[3];
    const float* psf   = (const float*)d_in[4];
    const float* Wp    = (const float*)d_in[5];
    const float* bp    = (const float*)d_in[6];
    const float* Wc    = (const float*)d_in[7];
    const float* bc    = (const float*)d_in[8];
    const float* W1    = (const float*)d_in[9];
    const float* b1    = (const float*)d_in[10];
    const float* W2    = (const float*)d_in[11];
    const float* b2    = (const float*)d_in[12];
    const float* Wout  = (const float*)d_in[13];
    const float* bout  = (const float*)d_in[14];
    float* out = (float*)d_out;

    char* ws = (char*)d_ws;
    float*    cond = (float*)ws;                         // 32768 B
    _Float16* Wt1  = (_Float16*)(ws + 32768);            // 131072 B
    _Float16* Wt2  = (_Float16*)(ws + 32768 + 131072);   // 131072 B

    hipLaunchKernelGGL(prep_weights_k, dim3(256), dim3(256), 0, stream, W1, W2, Wt1, Wt2);
    hipLaunchKernelGGL(prep_cond_k, dim3(B_ * M_), dim3(H_), 0, stream, psf, Wc, bc, cond);
    hipLaunchKernelGGL(occ_main_k, dim3(ROWS_ / TM_), dim3(256), 0, stream,
                       pts, trans, rots, scal, Wp, bp, b1, b2, Wout, bout,
                       cond, Wt1, Wt2, out);
}

// Round 2
// 244.240 us; speedup vs baseline: 1.0956x; 1.0956x over previous
//
#include <hip/hip_runtime.h>
#include <hip/hip_fp16.h>
#include <math.h>

// Problem constants (fixed by setup_inputs)
#define B_   2
#define N_   256
#define P_   32
#define M_   16
#define C_   128
#define H_   256
#define NP_  (N_ * P_)          // 8192 points per batch
#define ROWS_ (B_ * NP_ * M_)   // 262144
#define TM_  64                 // rows per block
#define LDA_ (H_ + 8)           // f16 leading dim pad

typedef _Float16 half8 __attribute__((ext_vector_type(8)));
typedef float f32x4 __attribute__((ext_vector_type(4)));

// ---------------- P1: LDS-tiled transpose W1/W2 -> [n][k] f16 ----------------
__global__ void prep_transpose_k(const float* __restrict__ W1, const float* __restrict__ W2,
                                 _Float16* __restrict__ Wt1, _Float16* __restrict__ Wt2) {
    __shared__ float t[64][65];
    const int id = blockIdx.x;              // 32 blocks: 2 mats x 16 tiles
    const float* W = (id & 1) ? W2 : W1;
    _Float16* Wt = (id & 1) ? Wt2 : Wt1;
    const int tile = id >> 1, I = tile >> 2, J = tile & 3;   // I: k-tile, J: n-tile
    const int r = threadIdx.x >> 6, c = threadIdx.x & 63;
    #pragma unroll
    for (int p = 0; p < 16; ++p)
        t[p * 4 + r][c] = W[(I * 64 + p * 4 + r) * H_ + J * 64 + c];
    __syncthreads();
    #pragma unroll
    for (int p = 0; p < 16; ++p)
        Wt[(J * 64 + p * 4 + r) * H_ + I * 64 + c] = (_Float16)t[c][p * 4 + r];
}

// ------- P2: cond = psf@Wc + bc (+bp fold) -> B0t rows; Wp -> B0t rows 0..2 ---
// B0t layout: [b][n=256][k=32] f16.  k=0..2: Wp^T; k=3+m: cond[b,m,:]+bp; k>=19: 0
__global__ void prep_cond_k(const float* __restrict__ psf, const float* __restrict__ Wc,
                            const float* __restrict__ bc, const float* __restrict__ Wp,
                            const float* __restrict__ bp, _Float16* __restrict__ B0t) {
    const int bm = blockIdx.x;              // 0..31
    const int b = bm >> 4, m = bm & 15;
    const int h = threadIdx.x;              // 0..255
    const float* p = psf + bm * C_;
    float acc = bc[h];
    for (int c = 0; c < C_; ++c) acc += p[c] * Wc[c * H_ + h];
    _Float16* dst = B0t + (b * H_ + h) * 32;
    dst[3 + m] = (_Float16)(acc + bp[h]);
    if (m == 0) {
        dst[0] = (_Float16)Wp[h];
        dst[1] = (_Float16)Wp[H_ + h];
        dst[2] = (_Float16)Wp[2 * H_ + h];
        #pragma unroll
        for (int k = 19; k < 32; ++k) dst[k] = (_Float16)0.0f;
    }
}

// ---------------- main fused kernel ------------------------------------------
__global__ __launch_bounds__(256, 2)
void occ_main_k(const float* __restrict__ pts,  const float* __restrict__ trans,
                const float* __restrict__ rots, const float* __restrict__ scal,
                const float* __restrict__ b1v,  const float* __restrict__ b2v,
                const float* __restrict__ Wout, const float* __restrict__ bout,
                const _Float16* __restrict__ Wt1, const _Float16* __restrict__ Wt2,
                const _Float16* __restrict__ B0t, float* __restrict__ out) {
    __shared__ __align__(16) _Float16 sA0[TM_][32];     // [x0,x1,x2,onehot16,pad] f16
    __shared__ __align__(16) _Float16 sAbuf[TM_][LDA_]; // relu(net0), then relu(h1)
    __shared__ float sR[M_][9];
    __shared__ float sT[M_][3];
    __shared__ float sS[M_][3];
    __shared__ float sFell[TM_];
    __shared__ float sPart[TM_][4];

    const int tid  = threadIdx.x;
    const int base = blockIdx.x * TM_;
    const int b    = base >> 17;            // /(NP_*M_) = /131072

    if (tid < M_) {
        const int m = tid;
        const float* q = rots + (b * M_ + m) * 4;
        float w = q[0], x = q[1], y = q[2], z = q[3];
        float nrm = sqrtf(w * w + x * x + y * y + z * z);
        w /= nrm; x /= nrm; y /= nrm; z /= nrm;
        sR[m][0] = 1.0f - 2.0f * (y * y + z * z);
        sR[m][1] = 2.0f * (x * y - w * z);
        sR[m][2] = 2.0f * (x * z + w * y);
        sR[m][3] = 2.0f * (x * y + w * z);
        sR[m][4] = 1.0f - 2.0f * (x * x + z * z);
        sR[m][5] = 2.0f * (y * z - w * x);
        sR[m][6] = 2.0f * (x * z - w * y);
        sR[m][7] = 2.0f * (y * z + w * x);
        sR[m][8] = 1.0f - 2.0f * (x * x + y * y);
        const float* tp = trans + (b * M_ + m) * 3;
        sT[m][0] = tp[0]; sT[m][1] = tp[1]; sT[m][2] = tp[2];
        const float* sp = scal + (b * M_ + m) * 3;
        sS[m][0] = sp[0]; sS[m][1] = sp[1]; sS[m][2] = sp[2];
    }
    __syncthreads();

    // ---- stage A: build A0 rows (f16) + F_ell (fp32, contract off) ----
    {
        const int r  = tid >> 2;            // 0..63
        const int kg = tid & 3;             // which 8-wide k chunk
        const int rg = base + r;
        const int m  = rg & (M_ - 1);
        half8 av;
        #pragma unroll
        for (int j = 0; j < 8; ++j) av[j] = (_Float16)0.0f;
        if (kg == 0) {
            #pragma clang fp contract(off)
            const int np = (rg >> 4) & (NP_ - 1);
            const float* p = pts + (b * NP_ + np) * 3;
            float x0 = p[0] - sT[m][0];
            float x1 = p[1] - sT[m][1];
            float x2 = p[2] - sT[m][2];
            float t0 = sR[m][0] * x0 + sR[m][1] * x1 + sR[m][2] * x2;
            float t1 = sR[m][3] * x0 + sR[m][4] * x1 + sR[m][5] * x2;
            float t2 = sR[m][6] * x0 + sR[m][7] * x1 + sR[m][8] * x2;
            float v0 = t0 / sS[m][0];
            float v1 = t1 / sS[m][1];
            float v2 = t2 / sS[m][2];
            sFell[r] = v0 * v0 + v1 * v1 + v2 * v2;
            av[0] = (_Float16)t0; av[1] = (_Float16)t1; av[2] = (_Float16)t2;
            #pragma unroll
            for (int j = 3; j < 8; ++j) av[j] = (m == j - 3) ? (_Float16)1.0f : (_Float16)0.0f;
        } else if (kg == 1) {               // k=8..15 -> m=5..12
            #pragma unroll
            for (int j = 0; j < 8; ++j) av[j] = (m == 5 + j) ? (_Float16)1.0f : (_Float16)0.0f;
        } else if (kg == 2) {               // k=16..18 -> m=13..15
            #pragma unroll
            for (int j = 0; j < 3; ++j) av[j] = (m == 13 + j) ? (_Float16)1.0f : (_Float16)0.0f;
        }
        *(half8*)&sA0[r][kg * 8] = av;
    }
    __syncthreads();

    const int w    = tid >> 6;
    const int lane = tid & 63;
    const int quad = lane >> 4;
    const int ln   = lane & 15;
    const f32x4 zero = {0.0f, 0.0f, 0.0f, 0.0f};

    // ---- GEMM 0: net0 = A0 @ B0  (K=32, biases+cond folded into B0) ----
    f32x4 acc0[4][4];
    {
        half8 a0[4], b0[4];
        #pragma unroll
        for (int rt = 0; rt < 4; ++rt)
            a0[rt] = *(const half8*)&sA0[rt * 16 + ln][quad * 8];
        const _Float16* B0w = B0t + (b * H_ + w * 64) * 32 + quad * 8;
        #pragma unroll
        for (int tc = 0; tc < 4; ++tc)
            b0[tc] = *(const half8*)(B0w + (tc * 16 + ln) * 32);
        #pragma unroll
        for (int rt = 0; rt < 4; ++rt)
            #pragma unroll
            for (int tc = 0; tc < 4; ++tc)
                acc0[rt][tc] = __builtin_amdgcn_mfma_f32_16x16x32_f16(a0[rt], b0[tc], zero, 0, 0, 0);
    }

    // ep0: relu(net0) -> sAbuf (acc0 keeps pre-relu net0 for the residual)
    #pragma unroll
    for (int tc = 0; tc < 4; ++tc) {
        const int col = w * 64 + tc * 16 + ln;
        #pragma unroll
        for (int rt = 0; rt < 4; ++rt)
            #pragma unroll
            for (int rg = 0; rg < 4; ++rg) {
                float v = acc0[rt][tc][rg];
                v = v > 0.0f ? v : 0.0f;
                sAbuf[rt * 16 + quad * 4 + rg][col] = (_Float16)v;
            }
    }
    __syncthreads();

    // ---- GEMM 1: h1 = relu(net0) @ W1 + b1 (b1 in acc init) ----
    f32x4 acc1[4][4];
    #pragma unroll
    for (int tc = 0; tc < 4; ++tc) {
        const float bb = b1v[w * 64 + tc * 16 + ln];
        const f32x4 bv = {bb, bb, bb, bb};
        #pragma unroll
        for (int rt = 0; rt < 4; ++rt) acc1[rt][tc] = bv;
    }
    {
        const _Float16* Wb1 = Wt1 + (w * 64) * H_;
        #pragma unroll
        for (int kc = 0; kc < 8; ++kc) {
            const int k0 = kc * 32 + quad * 8;
            half8 a[4], bf[4];
            #pragma unroll
            for (int rt = 0; rt < 4; ++rt)
                a[rt] = *(const half8*)&sAbuf[rt * 16 + ln][k0];
            #pragma unroll
            for (int tc = 0; tc < 4; ++tc)
                bf[tc] = *(const half8*)(Wb1 + (tc * 16 + ln) * H_ + k0);
            #pragma unroll
            for (int rt = 0; rt < 4; ++rt)
                #pragma unroll
                for (int tc = 0; tc < 4; ++tc)
                    acc1[rt][tc] = __builtin_amdgcn_mfma_f32_16x16x32_f16(a[rt], bf[tc], acc1[rt][tc], 0, 0, 0);
        }
    }
    __syncthreads();   // all GEMM1 reads of sAbuf complete before overwrite

    // ep1: relu(h1) -> sAbuf
    #pragma unroll
    for (int tc = 0; tc < 4; ++tc) {
        const int col = w * 64 + tc * 16 + ln;
        #pragma unroll
        for (int rt = 0; rt < 4; ++rt)
            #pragma unroll
            for (int rg = 0; rg < 4; ++rg) {
                float v = acc1[rt][tc][rg];
                v = v > 0.0f ? v : 0.0f;
                sAbuf[rt * 16 + quad * 4 + rg][col] = (_Float16)v;
            }
    }
    __syncthreads();

    // ---- GEMM 2: net = net0 + b2 + relu(h1) @ W2  (accumulate into acc0) ----
    #pragma unroll
    for (int tc = 0; tc < 4; ++tc) {
        const float bb = b2v[w * 64 + tc * 16 + ln];
        const f32x4 bv = {bb, bb, bb, bb};
        #pragma unroll
        for (int rt = 0; rt < 4; ++rt) acc0[rt][tc] += bv;
    }
    {
        const _Float16* Wb2 = Wt2 + (w * 64) * H_;
        #pragma unroll
        for (int kc = 0; kc < 8; ++kc) {
            const int k0 = kc * 32 + quad * 8;
            half8 a[4], bf[4];
            #pragma unroll
            for (int rt = 0; rt < 4; ++rt)
                a[rt] = *(const half8*)&sAbuf[rt * 16 + ln][k0];
            #pragma unroll
            for (int tc = 0; tc < 4; ++tc)
                bf[tc] = *(const half8*)(Wb2 + (tc * 16 + ln) * H_ + k0);
            #pragma unroll
            for (int rt = 0; rt < 4; ++rt)
                #pragma unroll
                for (int tc = 0; tc < 4; ++tc)
                    acc0[rt][tc] = __builtin_amdgcn_mfma_f32_16x16x32_f16(a[rt], bf[tc], acc0[rt][tc], 0, 0, 0);
        }
    }

    // ep2: rowsum of relu(net)*Wout, reduce 16 lanes then cross-wave
    float rowsum[4][4];
    #pragma unroll
    for (int rt = 0; rt < 4; ++rt)
        #pragma unroll
        for (int rg = 0; rg < 4; ++rg) rowsum[rt][rg] = 0.0f;

    #pragma unroll
    for (int tc = 0; tc < 4; ++tc) {
        const float wo = Wout[w * 64 + tc * 16 + ln];
        #pragma unroll
        for (int rt = 0; rt < 4; ++rt)
            #pragma unroll
            for (int rg = 0; rg < 4; ++rg) {
                float net = acc0[rt][tc][rg];
                net = net > 0.0f ? net : 0.0f;
                rowsum[rt][rg] += net * wo;
            }
    }

    #pragma unroll
    for (int rt = 0; rt < 4; ++rt)
        #pragma unroll
        for (int rg = 0; rg < 4; ++rg) {
            float v = rowsum[rt][rg];
            v += __shfl_xor(v, 1, 16);
            v += __shfl_xor(v, 2, 16);
            v += __shfl_xor(v, 4, 16);
            v += __shfl_xor(v, 8, 16);
            if (ln == 0) sPart[rt * 16 + quad * 4 + rg][w] = v;
        }
    __syncthreads();

    if (tid < TM_) {
        float occ = sPart[tid][0] + sPart[tid][1] + sPart[tid][2] + sPart[tid][3] + bout[0];
        float F = (sFell[tid] <= 1.0f) ? occ : -100.0f;
        out[base + tid] = 1.0f / (1.0f + __expf(-10.0f * F));
    }
}

// ---------------- launch ------------------------------------------------------
extern "C" void kernel_launch(void* const* d_in, const int* in_sizes, int n_in,
                              void* d_out, int out_size, void* d_ws, size_t ws_size,
                              hipStream_t stream) {
    const float* pts   = (const float*)d_in[0];
    const float* trans = (const float*)d_in[1];
    const float* rots  = (const float*)d_in[2];
    const float* scal  = (const float*)d_in[3];
    const float* psf   = (const float*)d_in[4];
    const float* Wp    = (const float*)d_in[5];
    const float* bp    = (const float*)d_in[6];
    const float* Wc    = (const float*)d_in[7];
    const float* bc    = (const float*)d_in[8];
    const float* W1    = (const float*)d_in[9];
    const float* b1    = (const float*)d_in[10];
    const float* W2    = (const float*)d_in[11];
    const float* b2    = (const float*)d_in[12];
    const float* Wout  = (const float*)d_in[13];
    const float* bout  = (const float*)d_in[14];
    float* out = (float*)d_out;

    char* ws = (char*)d_ws;
    _Float16* Wt1 = (_Float16*)ws;                       // 131072 B
    _Float16* Wt2 = (_Float16*)(ws + 131072);            // 131072 B
    _Float16* B0t = (_Float16*)(ws + 262144);            // 32768 B

    hipLaunchKernelGGL(prep_transpose_k, dim3(32), dim3(256), 0, stream, W1, W2, Wt1, Wt2);
    hipLaunchKernelGGL(prep_cond_k, dim3(B_ * M_), dim3(256), 0, stream, psf, Wc, bc, Wp, bp, B0t);
    hipLaunchKernelGGL(occ_main_k, dim3(ROWS_ / TM_), dim3(256), 0, stream,
                       pts, trans, rots, scal, b1, b2, Wout, bout, Wt1, Wt2, B0t, out);
}